// Round 1
// baseline (15483.012 us; speedup 1.0000x reference)
//
#include <hip/hip_runtime.h>
#include <stdint.h>
#include <stddef.h>

#define B_ 64
#define T_ 512
#define DIN 256
#define H_ 512
#define G4 2048      // 4*H
#define NWG 32       // recurrence workgroups (512 h-cols / 16 per WG)

typedef __attribute__((ext_vector_type(8))) short short8;
typedef __attribute__((ext_vector_type(4))) float f32x4;

__device__ __forceinline__ unsigned short f2bf(float f) {
  union { float f; unsigned u; } v; v.f = f;
  return (unsigned short)((v.u + 0x7fffu + ((v.u >> 16) & 1u)) >> 16);
}
__device__ __forceinline__ float bf2f(unsigned short s) {
  union { unsigned u; float f; } v; v.u = ((unsigned)s) << 16; return v.f;
}
__device__ __forceinline__ float sigmoidf_(float x) { return 1.f / (1.f + __expf(-x)); }
__device__ __forceinline__ float tanhf_(float x) { return 1.f - 2.f / (__expf(2.f * x) + 1.f); }

__device__ __forceinline__ float ldx(const float* p) { return *p; }
__device__ __forceinline__ float ldx(const unsigned short* p) { return bf2f(*p); }
__device__ __forceinline__ void stc(float* p, float v) { *p = v; }
__device__ __forceinline__ void stc(unsigned short* p, float v) { *p = f2bf(v); }

// ---------------- converts ----------------
// x [B,T,DIN] f32  ->  xT [T,B,DIN] bf16
__global__ void k_convert_x(const float* __restrict__ x, unsigned short* __restrict__ xT) {
  const int nq = T_ * B_ * DIN / 4;
  for (int q = blockIdx.x * blockDim.x + threadIdx.x; q < nq; q += gridDim.x * blockDim.x) {
    int e = q * 4;
    int d = e % DIN;
    int row = e / DIN;            // t*B + b
    int b = row & (B_ - 1), t = row / B_;
    float4 v = *(const float4*)(x + ((size_t)b * T_ + t) * DIN + d);
    unsigned short o[4] = { f2bf(v.x), f2bf(v.y), f2bf(v.z), f2bf(v.w) };
    *(uint2*)(xT + (size_t)row * DIN + d) = *(const uint2*)o;
  }
}

__global__ void k_convert_w(const float* __restrict__ w, unsigned short* __restrict__ o, int n) {
  const int nq = n / 4;
  for (int q = blockIdx.x * blockDim.x + threadIdx.x; q < nq; q += gridDim.x * blockDim.x) {
    float4 v = *(const float4*)(w + q * 4);
    unsigned short s[4] = { f2bf(v.x), f2bf(v.y), f2bf(v.z), f2bf(v.w) };
    *(uint2*)(o + q * 4) = *(const uint2*)s;
  }
}

// ---------------- GEMM: C[M,2048] = A[M,K](bf16) @ W[2048,K]^T(bf16) + (ba+bb) ----------------
// 128x128 tile, 4 waves, BK=64, fragment-packed LDS staging (conflict-free frag reads).
template <typename XGT>
__global__ __launch_bounds__(256, 1) void k_gemm_bias(
    const unsigned short* __restrict__ A, const unsigned short* __restrict__ Bw,
    const float* __restrict__ ba, const float* __restrict__ bb,
    XGT* __restrict__ C, int K, int ntn) {
  __shared__ unsigned short lds[16384];  // A frags [0,8192), B frags [8192,16384)
  const int bid = blockIdx.x;
  const int nt = bid % ntn, mt = bid / ntn;
  const int tid = threadIdx.x;
  const int lane = tid & 63, wv = tid >> 6;
  const int wm = wv & 1, wn = wv >> 1;
  f32x4 acc[4][4] = {};
  const int nkt = K >> 6;
  const size_t ar0 = (size_t)mt * 128, br0 = (size_t)nt * 128;
  for (int kt = 0; kt < nkt; ++kt) {
    __syncthreads();
#pragma unroll
    for (int jj = 0; jj < 4; ++jj) {
      int g = tid + jj * 256;           // 0..1023 granules (16B each)
      int row = g >> 3, gc = g & 7;     // row in tile, 16B-granule in row
      int dst = (((row >> 4) * 2 + (gc >> 2)) * 64 + ((row & 15) + ((gc & 3) << 4))) * 8;
      uint4 va = *(const uint4*)(A + (ar0 + row) * (size_t)K + (size_t)kt * 64 + gc * 8);
      *(uint4*)&lds[dst] = va;
      uint4 vb = *(const uint4*)(Bw + (br0 + row) * (size_t)K + (size_t)kt * 64 + gc * 8);
      *(uint4*)&lds[8192 + dst] = vb;
    }
    __syncthreads();
#pragma unroll
    for (int kk = 0; kk < 2; ++kk) {
      short8 af[4], bf[4];
#pragma unroll
      for (int m = 0; m < 4; ++m)
        af[m] = *(const short8*)&lds[(((wm * 4 + m) * 2 + kk) * 64 + lane) * 8];
#pragma unroll
      for (int n = 0; n < 4; ++n)
        bf[n] = *(const short8*)&lds[8192 + (((wn * 4 + n) * 2 + kk) * 64 + lane) * 8];
#pragma unroll
      for (int m = 0; m < 4; ++m)
#pragma unroll
        for (int n = 0; n < 4; ++n)
          acc[m][n] = __builtin_amdgcn_mfma_f32_16x16x32_bf16(af[m], bf[n], acc[m][n], 0, 0, 0);
    }
  }
#pragma unroll
  for (int n = 0; n < 4; ++n) {
    int col = (int)br0 + wn * 64 + n * 16 + (lane & 15);
    float bsum = ba[col] + bb[col];
#pragma unroll
    for (int m = 0; m < 4; ++m) {
      size_t row = ar0 + wm * 64 + m * 16 + ((lane >> 4) * 4);
#pragma unroll
      for (int r = 0; r < 4; ++r)
        stc(C + (row + r) * G4 + col, acc[m][n][r] + bsum);
    }
  }
}

// ---------------- persistent LSTM recurrence ----------------
// 32 WGs x 1 wave. WG wg owns h-cols [wg*16, wg*16+16) for ALL 64 batches.
// w_hh (fp32 global) is packed once into per-lane MFMA B-fragments in LDS (bf16).
// h exchanged through h_out (bf16, full history), device-scope barrier per tick.
template <typename XGT>
__global__ __launch_bounds__(64, 1) void k_lstm(
    const XGT* __restrict__ xg,          // [T,B,4H]
    const float* __restrict__ w_hh,      // [4H,H] fp32
    unsigned short* __restrict__ h_out,  // [T,B,H] bf16
    int* __restrict__ bar) {             // bar[0]=cnt, bar[16]=gen
  __shared__ unsigned short wf[64 * 64 * 8];  // 64 frags x 64 lanes x 8 bf16 = 64KB
  const int wg = blockIdx.x;
  const int lane = threadIdx.x;
  // ---- pack weights: frag i = (section s = i>>4, k-chunk kk = i&15) ----
  {
    const int j = lane & 15, kg = lane >> 4;
    for (int i = 0; i < 64; ++i) {
      int s = i >> 4, kk = i & 15;
      const float* src = w_hh + (size_t)(s * H_ + wg * 16 + j) * H_ + kk * 32 + kg * 8;
      float4 v0 = *(const float4*)src;
      float4 v1 = *(const float4*)(src + 4);
      unsigned short o[8] = { f2bf(v0.x), f2bf(v0.y), f2bf(v0.z), f2bf(v0.w),
                              f2bf(v1.x), f2bf(v1.y), f2bf(v1.z), f2bf(v1.w) };
      *(uint4*)&wf[((size_t)i * 64 + lane) * 8] = *(const uint4*)o;
    }
  }
  __syncthreads();

  float c[4][4] = {};     // [m][r] cell state, fp32
  float xr[4][4][4];      // [m][r][s] prefetched xg
  {
    const XGT* base = xg + (size_t)((lane >> 4) * 4) * G4 + wg * 16 + (lane & 15);
#pragma unroll
    for (int m = 0; m < 4; ++m)
#pragma unroll
      for (int r = 0; r < 4; ++r)
#pragma unroll
        for (int s = 0; s < 4; ++s)
          xr[m][r][s] = ldx(base + (size_t)(m * 16 + r) * G4 + s * H_);
  }

  for (int t = 0; t < T_; ++t) {
    f32x4 acc[4][4] = {};  // [m][s]
    if (t > 0) {
      const unsigned short* hp = h_out + (size_t)(t - 1) * (B_ * H_);
      const unsigned short* hl = hp + (size_t)(lane & 15) * H_ + (lane >> 4) * 8;
#pragma unroll
      for (int kk = 0; kk < 16; ++kk) {
        short8 a[4];
#pragma unroll
        for (int m = 0; m < 4; ++m)
          a[m] = *(const short8*)(hl + (size_t)(m * 16) * H_ + kk * 32);
#pragma unroll
        for (int m = 0; m < 4; ++m)
#pragma unroll
          for (int s = 0; s < 4; ++s) {
            short8 b = *(const short8*)&wf[((size_t)(s * 16 + kk) * 64 + lane) * 8];
            acc[m][s] = __builtin_amdgcn_mfma_f32_16x16x32_bf16(a[m], b, acc[m][s], 0, 0, 0);
          }
      }
    }
    // gates -> activations -> state -> h store
    unsigned short* hw = h_out + (size_t)t * (B_ * H_) + wg * 16 + (lane & 15);
#pragma unroll
    for (int m = 0; m < 4; ++m)
#pragma unroll
      for (int r = 0; r < 4; ++r) {
        float gi = xr[m][r][0] + acc[m][0][r];
        float gf = xr[m][r][1] + acc[m][1][r];
        float gg = xr[m][r][2] + acc[m][2][r];
        float go = xr[m][r][3] + acc[m][3][r];
        float iv = sigmoidf_(gi);
        float fv = sigmoidf_(gf);
        float gv = tanhf_(gg);
        float ov = sigmoidf_(go);
        float cn = fv * c[m][r] + iv * gv;
        c[m][r] = cn;
        float hv = ov * tanhf_(cn);
        hw[(size_t)(m * 16 + (lane >> 4) * 4 + r) * H_] = f2bf(hv);
      }

    if (t + 1 < T_) {
      // prefetch next tick's xg BEFORE the barrier (independent of h) to hide HBM latency
      {
        const XGT* base = xg + (size_t)(t + 1) * (B_ * G4) +
                          (size_t)((lane >> 4) * 4) * G4 + wg * 16 + (lane & 15);
#pragma unroll
        for (int m = 0; m < 4; ++m)
#pragma unroll
          for (int r = 0; r < 4; ++r)
#pragma unroll
            for (int s = 0; s < 4; ++s)
              xr[m][r][s] = ldx(base + (size_t)(m * 16 + r) * G4 + s * H_);
      }
      // device-scope generation barrier across NWG workgroups
      if (lane == 0) {
        __threadfence();  // release h stores to LLC
        int g0 = __hip_atomic_load(bar + 16, __ATOMIC_RELAXED, __HIP_MEMORY_SCOPE_AGENT);
        int arr = __hip_atomic_fetch_add(bar, 1, __ATOMIC_ACQ_REL, __HIP_MEMORY_SCOPE_AGENT);
        if (arr == NWG - 1) {
          __hip_atomic_store(bar, 0, __ATOMIC_RELAXED, __HIP_MEMORY_SCOPE_AGENT);
          __hip_atomic_fetch_add(bar + 16, 1, __ATOMIC_RELEASE, __HIP_MEMORY_SCOPE_AGENT);
        } else {
          while (__hip_atomic_load(bar + 16, __ATOMIC_ACQUIRE, __HIP_MEMORY_SCOPE_AGENT) == g0) {
            __builtin_amdgcn_s_sleep(1);
          }
        }
      }
      __syncthreads();
    }
  }
}

// ---------------- final FC + sigmoid ----------------
__global__ void k_fc(const unsigned short* __restrict__ h, const float* __restrict__ w,
                     const float* __restrict__ bfc, float* __restrict__ out) {
  int b = threadIdx.x;
  if (b < B_) {
    const unsigned short* hb = h + (size_t)b * H_;
    float s = 0.f;
    for (int j = 0; j < H_; ++j) s += bf2f(hb[j]) * w[j];
    out[b] = sigmoidf_(s + bfc[0]);
  }
}

extern "C" void kernel_launch(void* const* d_in, const int* in_sizes, int n_in,
                              void* d_out, int out_size, void* d_ws, size_t ws_size,
                              hipStream_t stream) {
  (void)in_sizes; (void)n_in; (void)out_size;
  const float* x    = (const float*)d_in[0];
  const float* wih0 = (const float*)d_in[1];
  const float* whh0 = (const float*)d_in[2];
  const float* bih0 = (const float*)d_in[3];
  const float* bhh0 = (const float*)d_in[4];
  const float* wih1 = (const float*)d_in[5];
  const float* whh1 = (const float*)d_in[6];
  const float* bih1 = (const float*)d_in[7];
  const float* bhh1 = (const float*)d_in[8];
  const float* wfc  = (const float*)d_in[9];
  const float* bfc  = (const float*)d_in[10];
  float* out = (float*)d_out;

  char* ws = (char*)d_ws;
  size_t off = 256;                         // [0,256): barrier counters
  int* bar = (int*)ws;
  unsigned short* xT = (unsigned short*)(ws + off);    off += (size_t)T_ * B_ * DIN * 2;   // 16.78MB
  unsigned short* wih0b = (unsigned short*)(ws + off); off += (size_t)G4 * DIN * 2;        // 1.05MB
  unsigned short* wih1b = (unsigned short*)(ws + off); off += (size_t)G4 * H_ * 2;         // 2.10MB
  unsigned short* h0 = (unsigned short*)(ws + off);    off += (size_t)T_ * B_ * H_ * 2;    // 33.55MB
  unsigned short* h1 = (unsigned short*)(ws + off);    off += (size_t)T_ * B_ * H_ * 2;    // 33.55MB
  size_t xg_off = off;
  const size_t need_f32 = xg_off + (size_t)T_ * B_ * G4 * 4;  // +268.4MB

  const int gemm_grid = (T_ * B_ / 128) * (G4 / 128);  // 4096
  const int ntn = G4 / 128;                            // 16

  hipMemsetAsync(bar, 0, 256, stream);
  k_convert_x<<<2048, 256, 0, stream>>>(x, xT);
  k_convert_w<<<512, 256, 0, stream>>>(wih0, wih0b, G4 * DIN);
  k_convert_w<<<1024, 256, 0, stream>>>(wih1, wih1b, G4 * H_);

  if (ws_size >= need_f32) {
    float* xgbuf = (float*)(ws + xg_off);
    k_gemm_bias<float><<<gemm_grid, 256, 0, stream>>>(xT, wih0b, bih0, bhh0, xgbuf, DIN, ntn);
    k_lstm<float><<<NWG, 64, 0, stream>>>(xgbuf, whh0, h0, bar);
    k_gemm_bias<float><<<gemm_grid, 256, 0, stream>>>(h0, wih1b, bih1, bhh1, xgbuf, H_, ntn);
    k_lstm<float><<<NWG, 64, 0, stream>>>(xgbuf, whh1, h1, bar + 32);
  } else {
    unsigned short* xgbuf = (unsigned short*)(ws + xg_off);
    k_gemm_bias<unsigned short><<<gemm_grid, 256, 0, stream>>>(xT, wih0b, bih0, bhh0, xgbuf, DIN, ntn);
    k_lstm<unsigned short><<<NWG, 64, 0, stream>>>(xgbuf, whh0, h0, bar);
    k_gemm_bias<unsigned short><<<gemm_grid, 256, 0, stream>>>(h0, wih1b, bih1, bhh1, xgbuf, H_, ntn);
    k_lstm<unsigned short><<<NWG, 64, 0, stream>>>(xgbuf, whh1, h1, bar + 32);
  }
  k_fc<<<1, 64, 0, stream>>>(h1 + (size_t)(T_ - 1) * B_ * H_, wfc, bfc, out);
}